// Round 4
// baseline (735.078 us; speedup 1.0000x reference)
//
#include <hip/hip_runtime.h>

#define NLVL 16
#define NTOT 1846083
#define NTILE 4376
#define NBLOCK 1094   // 4 wave-tiles per block

typedef float  f32x4  __attribute__((ext_vector_type(4)));
typedef __bf16 bf16x8 __attribute__((ext_vector_type(8)));
typedef __bf16 bf16x4 __attribute__((ext_vector_type(4)));
typedef unsigned int u32;
typedef unsigned int u32x4 __attribute__((ext_vector_type(4)));

// level tables (static in reference)
__constant__ int c_R[NLVL]   = {16,18,20,22,25,27,30,34,38,42,47,52,58,64,72,80};
__constant__ int c_off[NLVL] = {0,4096,9928,17928,28576,44201,63884,90884,130188,185060,259148,362971,503579,698691,960835,1334083};
__constant__ int c_czy[NLVL] = {4,5,5,6,7,7,8,9,10,11,12,13,15,16,18,20};   // ceil(R/4)  (4-row wave tiles)
__constant__ int c_cx[NLVL]  = {1,2,2,2,2,2,2,3,3,3,3,4,4,4,5,5};           // ceil(R/16) (x-tiles = z-chunks)
// wave-tiles ordered level 15 -> 0 (longest first); count[l] = 2*czy*cx*cx
__constant__ int c_base[17]  = {0,1000,1900,2412,2892,3308,3524,3722,3902,4064,4128,4184,4240,4288,4328,4368,4376};

// weight fragments: [level][kz(3)][pair(5)][lane(64)][8 bf16] = 240 KB
__device__ __align__(16) unsigned short g_bfrag[NLVL*3*5*64*8];

// ---------------------------------------------------------------------------
// Pack weights into MFMA A-operand fragments (weights-as-A, data-as-B).
// A[m=co][k]: m=lane&15, k=(lane>>4)*8+j; k -> tip=k>>4, ci=k&15;
// in-plane tap t2 = 2*pair + tip (t2==9 padded with zero weight).
// ---------------------------------------------------------------------------
__global__ void prep_bfrag(const float* __restrict__ wgt) {
    int tid = blockIdx.x * 256 + threadIdx.x;
    if (tid >= NLVL*3*5*64) return;
    int lane = tid & 63;
    int p    = (tid >> 6) % 5;
    int d    = (tid / (5*64)) % 3;
    int l    = tid / (3*5*64);
    int quad = lane >> 4, co = lane & 15;
    unsigned short v[8];
#pragma unroll
    for (int j = 0; j < 8; ++j) {
        int k   = quad*8 + j;
        int tip = k >> 4;
        int ci  = k & 15;
        int t2  = 2*p + tip;
        float f = (t2 < 9) ? wgt[((l*27 + d*9 + t2)*16 + ci)*16 + co] : 0.f;
        v[j] = __builtin_bit_cast(unsigned short, (__bf16)f);
    }
    u32x4 pk;
    pk[0] = (u32)v[0] | ((u32)v[1] << 16);
    pk[1] = (u32)v[2] | ((u32)v[3] << 16);
    pk[2] = (u32)v[4] | ((u32)v[5] << 16);
    pk[3] = (u32)v[6] | ((u32)v[7] << 16);
    *(u32x4*)&g_bfrag[(size_t)tid*8] = pk;
}

// ---------------------------------------------------------------------------
// Barrier-free streaming-z conv. Each WAVE owns a 16x * 4y tile and streams a
// 16-deep z-chunk independently: global->reg (2-set ping-pong) -> cvt -> bf16
// LDS plane (own 8KB region, 2-plane ping-pong) -> 20 ds_read_b128 -> 60 MFMA
// into 3 statically-rotated acc slots (6-body unroll: mod-3 slot x mod-2 buf).
// All sync intra-wave (counted waitcnt only). 3 waves/SIMD for latency cover.
// ---------------------------------------------------------------------------
__global__ __launch_bounds__(256, 3)
void conv_kernel(const float* __restrict__ in,
                 const float* __restrict__ bias,
                 float* __restrict__ out) {
    // per-wave 8KB region: two bf16 planes [yp 0..5][xp 0..17][ci 0..15] at +0/+4096
    __shared__ __align__(16) char slab[4*8192];

    const int t    = threadIdx.x;
    const int lane = t & 63;
    const int wv   = t >> 6;

    // bijective XCD-aware swizzle (NBLOCK % 8 != 0 -> m204 variant):
    // XCD xcd gets a contiguous chunk of ceil/floor(NBLOCK/8) blocks.
    int bswz;
    {
        const int q = NBLOCK / 8, r = NBLOCK % 8;
        int xcd = blockIdx.x % 8, i = blockIdx.x / 8;
        bswz = (xcd < r ? xcd * (q + 1) : r * (q + 1) + (xcd - r) * q) + i;
    }

    const int tid4 = bswz*4 + wv;
    int idx = 0;
#pragma unroll
    for (int i = 1; i < 16; ++i) if (tid4 >= c_base[i]) idx = i;
    const int l = 15 - idx;
    const int R = c_R[l], off = c_off[l], czy = c_czy[l], cx = c_cx[l];

    int local = tid4 - c_base[idx];
    int per_b = czy*cx*cx;
    int bb = local / per_b;         int r1 = local - bb*per_b;
    int zt = r1 / (czy*cx);         int r2 = r1 - zt*(czy*cx);
    int yt = r2 / cx;               int xt = r2 - yt*cx;
    const int z0 = zt*16;
    const int z1 = (z0 + 16 < R) ? z0 + 16 : R;
    const int y0 = yt*4, x0 = xt*16;
    const int steps = z1 - z0 + 2;

    const int quad = lane >> 4;
    const int m    = lane & 15;
    const int qh   = quad >> 1;

    // ---- weight fragments resident (15 x 16B per lane) ----
    bf16x8 bfr[15];
#pragma unroll
    for (int d = 0; d < 3; ++d)
#pragma unroll
        for (int p = 0; p < 5; ++p)
            bfr[d*5+p] = *(const bf16x8*)&g_bfrag[(size_t)(((l*3 + d)*5 + p)*64 + lane)*8];

    // ---- A-frag LDS base pointers (5 pairs; +PAR*4096 +r*576 folded as imm) ----
    const char* sbase = (const char*)slab + wv*8192;
    const char* arA[5];
    {
        const int T0[5] = {0, 64, 608, 1152, 1216};
        const int T1[5] = {32, 576, 640, 1184, 1216};
        const int ab = m*32 + (quad & 1)*16;
#pragma unroll
        for (int p = 0; p < 5; ++p) arA[p] = sbase + ab + (qh ? T1[p] : T0[p]);
    }
    char* wbase = (char*)slab + wv*8192 + lane*8;

    // ---- staging: plane = 432 f32x4 chunks; slot s covers chunk lane+s*64 ----
    const int  zsE = R*R*16;            // f32 elements per z-plane
    const u32  zsB = (u32)zsE*4;        // bytes per z-plane
    const long gstartE = ((long)bb*NTOT + off)*16;

    u32 cur[7]; bool okk[7];
#pragma unroll
    for (int s = 0; s < 7; ++s) {
        int c = lane + s*64;
        int yp = c/72; int rem = c - yp*72; int xp = rem>>2; int ci4 = (rem&3)<<2;
        int y = y0 + yp - 1, x = x0 + xp - 1;
        okk[s] = (c < 432) && ((unsigned)y < (unsigned)R) && ((unsigned)x < (unsigned)R);
        long e = gstartE + (long)(z0-1)*zsE + ((long)y*R + x)*16 + ci4;
        cur[s] = (u32)(e*4);            // byte offset; only deref'd when guarded valid
    }

    const f32x4 z4 = {0,0,0,0};
    f32x4 LA[7], LB[7];

    // ---- prologue: plane z0-1 -> LA -> buf0; plane z0 -> LB (held in regs) ----
    {
        const bool zrA = (z0 > 0);
#pragma unroll
        for (int s = 0; s < 7; ++s) { f32x4 v = z4; if (zrA && okk[s]) v = *(const f32x4*)((const char*)in + cur[s]); LA[s] = v; }
#pragma unroll
        for (int s = 0; s < 7; ++s) cur[s] += zsB;
#pragma unroll
        for (int s = 0; s < 7; ++s) { f32x4 v = z4; if (okk[s]) v = *(const f32x4*)((const char*)in + cur[s]); LB[s] = v; }
#pragma unroll
        for (int s = 0; s < 7; ++s) cur[s] += zsB;
#pragma unroll
        for (int s = 0; s < 7; ++s) {
            bf16x4 h = {(__bf16)LA[s][0],(__bf16)LA[s][1],(__bf16)LA[s][2],(__bf16)LA[s][3]};
            *(bf16x4*)(wbase + s*512) = h;
        }
    }

    const bool xok = (x0 + m) < R;
    bool ywr[4];
#pragma unroll
    for (int r = 0; r < 4; ++r) ywr[r] = (y0 + r) < R;
    const f32x4 bv4 = *(const f32x4*)(bias + (l << 4) + (quad << 2));

    float* so[4];
#pragma unroll
    for (int r = 0; r < 4; ++r)
        so[r] = out + gstartE + (((long)z0*R + (y0 + r))*(long)R + (x0 + m))*16 + (quad << 2);

    f32x4 acc0[4], acc1[4], acc2[4];
#pragma unroll
    for (int r = 0; r < 4; ++r) { acc0[r] = z4; acc1[r] = z4; acc2[r] = z4; }

    int zl = z0 + 1;   // plane loaded by the next body

    // Body II: loads plane zl into LN; computes plane z0-1+II from buf(PAR);
    // cvt-writes LO (plane z0+II) into buf(PAR^1); AZ completes out plane II-2.
#define BODY(II, PAR, LN, LO, AX, AY, AZ, ENST)                                         \
    {                                                                                   \
        const bool zr = (zl <= z1) && (zl < R);                                         \
        _Pragma("unroll")                                                               \
        for (int s = 0; s < 7; ++s) {                                                   \
            f32x4 v = z4;                                                               \
            if (zr && okk[s]) v = *(const f32x4*)((const char*)in + cur[s]);            \
            LN[s] = v;                                                                  \
        }                                                                               \
        { u32 a_ = zr ? zsB : 0u;                                                       \
          _Pragma("unroll") for (int s = 0; s < 7; ++s) cur[s] += a_; }                 \
        ++zl;                                                                           \
        _Pragma("unroll")                                                               \
        for (int p = 0; p < 5; ++p) {                                                   \
            _Pragma("unroll")                                                           \
            for (int r = 0; r < 4; ++r) {                                               \
                bf16x8 af = *(const bf16x8*)(arA[p] + (PAR)*4096 + r*576);              \
                AX[r] = __builtin_amdgcn_mfma_f32_16x16x32_bf16(bfr[p],    af, AX[r], 0,0,0); \
                AY[r] = __builtin_amdgcn_mfma_f32_16x16x32_bf16(bfr[5+p],  af, AY[r], 0,0,0); \
                AZ[r] = __builtin_amdgcn_mfma_f32_16x16x32_bf16(bfr[10+p], af, AZ[r], 0,0,0); \
            }                                                                           \
        }                                                                               \
        _Pragma("unroll")                                                               \
        for (int s = 0; s < 7; ++s) {                                                   \
            bf16x4 h = {(__bf16)LO[s][0],(__bf16)LO[s][1],(__bf16)LO[s][2],(__bf16)LO[s][3]}; \
            *(bf16x4*)(wbase + ((PAR)^1)*4096 + s*512) = h;                             \
        }                                                                               \
        if ((ENST) && (II) < steps) {                                                   \
            _Pragma("unroll")                                                           \
            for (int r = 0; r < 4; ++r) {                                               \
                if (ywr[r] && xok) { f32x4 o_ = AZ[r] + bv4; *(f32x4*)so[r] = o_; }     \
                so[r] += zsE;                                                           \
            }                                                                           \
        }                                                                               \
        _Pragma("unroll")                                                               \
        for (int r = 0; r < 4; ++r) AZ[r] = z4;                                         \
    }

    BODY(0, 0, LA, LB, acc0, acc2, acc1, 0)
    BODY(1, 1, LB, LA, acc1, acc0, acc2, 0)
    BODY(2, 0, LA, LB, acc2, acc1, acc0, 1)
    BODY(3, 1, LB, LA, acc0, acc2, acc1, 1)
    BODY(4, 0, LA, LB, acc1, acc0, acc2, 1)
    BODY(5, 1, LB, LA, acc2, acc1, acc0, 1)
#pragma unroll 1
    for (int i = 6; i < steps; i += 6) {
        BODY(i+0, 0, LA, LB, acc0, acc2, acc1, 1)
        BODY(i+1, 1, LB, LA, acc1, acc0, acc2, 1)
        BODY(i+2, 0, LA, LB, acc2, acc1, acc0, 1)
        BODY(i+3, 1, LB, LA, acc0, acc2, acc1, 1)
        BODY(i+4, 0, LA, LB, acc1, acc0, acc2, 1)
        BODY(i+5, 1, LB, LA, acc2, acc1, acc0, 1)
    }
#undef BODY
}

extern "C" void kernel_launch(void* const* d_in, const int* in_sizes, int n_in,
                              void* d_out, int out_size, void* d_ws, size_t ws_size,
                              hipStream_t stream) {
    const float* inp = (const float*)d_in[0];
    const float* wgt = (const float*)d_in[1];
    const float* bia = (const float*)d_in[2];
    float* out = (float*)d_out;
    prep_bfrag<<<dim3((NLVL*3*5*64 + 255)/256), dim3(256), 0, stream>>>(wgt);
    conv_kernel<<<dim3(NBLOCK), dim3(256), 0, stream>>>(inp, bia, out);
}

// Round 5
// 453.881 us; speedup vs baseline: 1.6195x; 1.6195x over previous
//
#include <hip/hip_runtime.h>

#define NLVL 16
#define NTOT 1846083
#define NTILE 8634    // 2-row wave-tiles
#define NBLOCK 2159   // 4 wave-tiles per block (2 idle waves at the end)

typedef float  f32x4  __attribute__((ext_vector_type(4)));
typedef __bf16 bf16x8 __attribute__((ext_vector_type(8)));
typedef __bf16 bf16x4 __attribute__((ext_vector_type(4)));
typedef unsigned int u32;
typedef unsigned int u32x4 __attribute__((ext_vector_type(4)));

// level tables (static in reference)
__constant__ int c_R[NLVL]   = {16,18,20,22,25,27,30,34,38,42,47,52,58,64,72,80};
__constant__ int c_off[NLVL] = {0,4096,9928,17928,28576,44201,63884,90884,130188,185060,259148,362971,503579,698691,960835,1334083};
__constant__ int c_czy[NLVL] = {8,9,10,11,13,14,15,17,19,21,24,26,29,32,36,40}; // ceil(R/2) (2-row wave tiles)
__constant__ int c_cx[NLVL]  = {1,2,2,2,2,2,2,3,3,3,3,4,4,4,5,5};               // ceil(R/16) (x-tiles = z-chunks)
// wave-tiles ordered level 15 -> 0 (longest first); count[l] = 2*czy*cx*cx
__constant__ int c_base[17]  = {0,2000,3800,4824,5752,6584,7016,7394,7736,8042,8162,8274,8378,8466,8546,8618,8634};

// weight fragments: [level][kz(3)][pair(5)][lane(64)][8 bf16] = 240 KB
__device__ __align__(16) unsigned short g_bfrag[NLVL*3*5*64*8];

// ---------------------------------------------------------------------------
// Pack weights into MFMA A-operand fragments (weights-as-A, data-as-B).
// A[m=co][k]: m=lane&15, k=(lane>>4)*8+j; k -> tip=k>>4, ci=k&15;
// in-plane tap t2 = 2*pair + tip (t2==9 padded with zero weight).
// ---------------------------------------------------------------------------
__global__ void prep_bfrag(const float* __restrict__ wgt) {
    int tid = blockIdx.x * 256 + threadIdx.x;
    if (tid >= NLVL*3*5*64) return;
    int lane = tid & 63;
    int p    = (tid >> 6) % 5;
    int d    = (tid / (5*64)) % 3;
    int l    = tid / (3*5*64);
    int quad = lane >> 4, co = lane & 15;
    unsigned short v[8];
#pragma unroll
    for (int j = 0; j < 8; ++j) {
        int k   = quad*8 + j;
        int tip = k >> 4;
        int ci  = k & 15;
        int t2  = 2*p + tip;
        float f = (t2 < 9) ? wgt[((l*27 + d*9 + t2)*16 + ci)*16 + co] : 0.f;
        v[j] = __builtin_bit_cast(unsigned short, (__bf16)f);
    }
    u32x4 pk;
    pk[0] = (u32)v[0] | ((u32)v[1] << 16);
    pk[1] = (u32)v[2] | ((u32)v[3] << 16);
    pk[2] = (u32)v[4] | ((u32)v[5] << 16);
    pk[3] = (u32)v[6] | ((u32)v[7] << 16);
    *(u32x4*)&g_bfrag[(size_t)tid*8] = pk;
}

// ---------------------------------------------------------------------------
// Barrier-free streaming-z conv, 2 output rows per wave (register-dieted so
// 3 waves/SIMD fit without spills). Each wave owns a 16x * 2y tile, streams a
// 16-deep z-chunk: global->reg (2-set ping-pong, 5 slots) -> cvt -> bf16 LDS
// plane (4.6KB region, 2-plane ping-pong) -> 10 ds_read_b128 -> 30 MFMA into
// 3 statically-rotated acc slots (6-body unroll). All sync intra-wave.
// ---------------------------------------------------------------------------
__global__ __launch_bounds__(256, 3)
void conv_kernel(const float* __restrict__ in,
                 const float* __restrict__ bias,
                 float* __restrict__ out) {
    // per-wave 4608B region: two bf16 planes [yp 0..3][xp 0..17][ci 0..15] at +0/+2304
    __shared__ __align__(16) char slab[4*4608];

    const int t    = threadIdx.x;
    const int lane = t & 63;
    const int wv   = t >> 6;

    // bijective XCD-aware swizzle (m204 variant, NBLOCK % 8 != 0)
    int bswz;
    {
        const int q = NBLOCK / 8, r = NBLOCK % 8;
        int xcd = blockIdx.x % 8, i = blockIdx.x / 8;
        bswz = (xcd < r ? xcd * (q + 1) : r * (q + 1) + (xcd - r) * q) + i;
    }

    const int tid4 = bswz*4 + wv;
    if (tid4 >= NTILE) return;
    int idx = 0;
#pragma unroll
    for (int i = 1; i < 16; ++i) if (tid4 >= c_base[i]) idx = i;
    const int l = 15 - idx;
    const int R = c_R[l], off = c_off[l], czy = c_czy[l], cx = c_cx[l];

    int local = tid4 - c_base[idx];
    int per_b = czy*cx*cx;
    int bb = local / per_b;         int r1 = local - bb*per_b;
    int zt = r1 / (czy*cx);         int r2 = r1 - zt*(czy*cx);
    int yt = r2 / cx;               int xt = r2 - yt*cx;
    const int z0 = zt*16;
    const int z1 = (z0 + 16 < R) ? z0 + 16 : R;
    const int y0 = yt*2, x0 = xt*16;
    const int steps = z1 - z0 + 2;

    const int quad = lane >> 4;
    const int m    = lane & 15;
    const int qh   = quad >> 1;

    // ---- weight fragments resident (15 x 16B per lane) ----
    bf16x8 bfr[15];
#pragma unroll
    for (int d = 0; d < 3; ++d)
#pragma unroll
        for (int p = 0; p < 5; ++p)
            bfr[d*5+p] = *(const bf16x8*)&g_bfrag[(size_t)(((l*3 + d)*5 + p)*64 + lane)*8];

    // ---- A-frag LDS base pointers (5 pairs; +PAR*2304 +r*576 folded as imm) ----
    const char* sbase = (const char*)slab + wv*4608;
    const char* arA[5];
    {
        const int T0[5] = {0, 64, 608, 1152, 1216};
        const int T1[5] = {32, 576, 640, 1184, 1216};
        const int ab = m*32 + (quad & 1)*16;
#pragma unroll
        for (int p = 0; p < 5; ++p) arA[p] = sbase + ab + (qh ? T1[p] : T0[p]);
    }
    char* wbase = (char*)slab + wv*4608 + lane*8;

    // ---- staging: plane = 288 f32x4 chunks (4yp x 18xp x 4 quads); 5 slots ----
    const int  zsE = R*R*16;            // f32 elements per z-plane
    const u32  zsB = (u32)zsE*4;        // bytes per z-plane
    const long gstartE = ((long)bb*NTOT + off)*16;

    u32 cur[5]; bool okk[5];
#pragma unroll
    for (int s = 0; s < 5; ++s) {
        int c = lane + s*64;
        int yp = c/72; int rem = c - yp*72; int xp = rem>>2; int ci4 = (rem&3)<<2;
        int y = y0 + yp - 1, x = x0 + xp - 1;
        okk[s] = (c < 288) && ((unsigned)y < (unsigned)R) && ((unsigned)x < (unsigned)R);
        long e = gstartE + (long)(z0-1)*zsE + ((long)y*R + x)*16 + ci4;
        cur[s] = (u32)(e*4);            // byte offset; only deref'd when guarded valid
    }
    const bool wr4 = (lane < 32);       // slot 4 valid chunks: c < 288

    const f32x4 z4 = {0,0,0,0};
    f32x4 LA[5], LB[5];

    // ---- prologue: plane z0-1 -> LA -> buf0; plane z0 -> LB (held in regs) ----
    {
        const bool zrA = (z0 > 0);
#pragma unroll
        for (int s = 0; s < 5; ++s) { f32x4 v = z4; if (zrA && okk[s]) v = *(const f32x4*)((const char*)in + cur[s]); LA[s] = v; }
#pragma unroll
        for (int s = 0; s < 5; ++s) cur[s] += zsB;
#pragma unroll
        for (int s = 0; s < 5; ++s) { f32x4 v = z4; if (okk[s]) v = *(const f32x4*)((const char*)in + cur[s]); LB[s] = v; }
#pragma unroll
        for (int s = 0; s < 5; ++s) cur[s] += zsB;
#pragma unroll
        for (int s = 0; s < 5; ++s) {
            if (s < 4 || wr4) {
                bf16x4 h = {(__bf16)LA[s][0],(__bf16)LA[s][1],(__bf16)LA[s][2],(__bf16)LA[s][3]};
                *(bf16x4*)(wbase + s*512) = h;
            }
        }
    }

    const bool xok = (x0 + m) < R;
    bool ywr[2];
#pragma unroll
    for (int r = 0; r < 2; ++r) ywr[r] = (y0 + r) < R;
    const f32x4 bv4 = *(const f32x4*)(bias + (l << 4) + (quad << 2));

    float* so[2];
#pragma unroll
    for (int r = 0; r < 2; ++r)
        so[r] = out + gstartE + (((long)z0*R + (y0 + r))*(long)R + (x0 + m))*16 + (quad << 2);

    f32x4 acc0[2], acc1[2], acc2[2];
#pragma unroll
    for (int r = 0; r < 2; ++r) { acc0[r] = z4; acc1[r] = z4; acc2[r] = z4; }

    int zl = z0 + 1;   // plane loaded by the next body

    // Body II: loads plane zl into LN; computes plane z0-1+II from buf(PAR);
    // cvt-writes LO (plane z0+II) into buf(PAR^1); AZ completes out plane II-2.
#define BODY(II, PAR, LN, LO, AX, AY, AZ, ENST)                                         \
    {                                                                                   \
        const bool zr = (zl <= z1) && (zl < R);                                         \
        _Pragma("unroll")                                                               \
        for (int s = 0; s < 5; ++s) {                                                   \
            f32x4 v = z4;                                                               \
            if (zr && okk[s]) v = *(const f32x4*)((const char*)in + cur[s]);            \
            LN[s] = v;                                                                  \
        }                                                                               \
        { u32 a_ = zr ? zsB : 0u;                                                       \
          _Pragma("unroll") for (int s = 0; s < 5; ++s) cur[s] += a_; }                 \
        ++zl;                                                                           \
        _Pragma("unroll")                                                               \
        for (int p = 0; p < 5; ++p) {                                                   \
            _Pragma("unroll")                                                           \
            for (int r = 0; r < 2; ++r) {                                               \
                bf16x8 af = *(const bf16x8*)(arA[p] + (PAR)*2304 + r*576);              \
                AX[r] = __builtin_amdgcn_mfma_f32_16x16x32_bf16(bfr[p],    af, AX[r], 0,0,0); \
                AY[r] = __builtin_amdgcn_mfma_f32_16x16x32_bf16(bfr[5+p],  af, AY[r], 0,0,0); \
                AZ[r] = __builtin_amdgcn_mfma_f32_16x16x32_bf16(bfr[10+p], af, AZ[r], 0,0,0); \
            }                                                                           \
        }                                                                               \
        _Pragma("unroll")                                                               \
        for (int s = 0; s < 5; ++s) {                                                   \
            if (s < 4 || wr4) {                                                         \
                bf16x4 h = {(__bf16)LO[s][0],(__bf16)LO[s][1],(__bf16)LO[s][2],(__bf16)LO[s][3]}; \
                *(bf16x4*)(wbase + ((PAR)^1)*2304 + s*512) = h;                         \
            }                                                                           \
        }                                                                               \
        if ((ENST) && (II) < steps) {                                                   \
            _Pragma("unroll")                                                           \
            for (int r = 0; r < 2; ++r) {                                               \
                if (ywr[r] && xok) { f32x4 o_ = AZ[r] + bv4; *(f32x4*)so[r] = o_; }     \
                so[r] += zsE;                                                           \
            }                                                                           \
        }                                                                               \
        _Pragma("unroll")                                                               \
        for (int r = 0; r < 2; ++r) AZ[r] = z4;                                         \
    }

    BODY(0, 0, LA, LB, acc0, acc2, acc1, 0)
    BODY(1, 1, LB, LA, acc1, acc0, acc2, 0)
    BODY(2, 0, LA, LB, acc2, acc1, acc0, 1)
    BODY(3, 1, LB, LA, acc0, acc2, acc1, 1)
    BODY(4, 0, LA, LB, acc1, acc0, acc2, 1)
    BODY(5, 1, LB, LA, acc2, acc1, acc0, 1)
#pragma unroll 1
    for (int i = 6; i < steps; i += 6) {
        BODY(i+0, 0, LA, LB, acc0, acc2, acc1, 1)
        BODY(i+1, 1, LB, LA, acc1, acc0, acc2, 1)
        BODY(i+2, 0, LA, LB, acc2, acc1, acc0, 1)
        BODY(i+3, 1, LB, LA, acc0, acc2, acc1, 1)
        BODY(i+4, 0, LA, LB, acc1, acc0, acc2, 1)
        BODY(i+5, 1, LB, LA, acc2, acc1, acc0, 1)
    }
#undef BODY
}

extern "C" void kernel_launch(void* const* d_in, const int* in_sizes, int n_in,
                              void* d_out, int out_size, void* d_ws, size_t ws_size,
                              hipStream_t stream) {
    const float* inp = (const float*)d_in[0];
    const float* wgt = (const float*)d_in[1];
    const float* bia = (const float*)d_in[2];
    float* out = (float*)d_out;
    prep_bfrag<<<dim3((NLVL*3*5*64 + 255)/256), dim3(256), 0, stream>>>(wgt);
    conv_kernel<<<dim3(NBLOCK), dim3(256), 0, stream>>>(inp, bia, out);
}

// Round 6
// 434.117 us; speedup vs baseline: 1.6933x; 1.0455x over previous
//
#include <hip/hip_runtime.h>

#define NLVL 16
#define NTOT 1846083
#define NTILE 4376
#define NBLOCK 1094   // 4 wave-tiles per block

typedef float  f32x4  __attribute__((ext_vector_type(4)));
typedef __bf16 bf16x8 __attribute__((ext_vector_type(8)));
typedef __bf16 bf16x4 __attribute__((ext_vector_type(4)));
typedef unsigned int u32;
typedef unsigned int u32x4 __attribute__((ext_vector_type(4)));

// level tables (static in reference)
__constant__ int c_R[NLVL]   = {16,18,20,22,25,27,30,34,38,42,47,52,58,64,72,80};
__constant__ int c_off[NLVL] = {0,4096,9928,17928,28576,44201,63884,90884,130188,185060,259148,362971,503579,698691,960835,1334083};
__constant__ int c_czy[NLVL] = {4,5,5,6,7,7,8,9,10,11,12,13,15,16,18,20};   // ceil(R/4)  (4-row wave tiles)
__constant__ int c_cx[NLVL]  = {1,2,2,2,2,2,2,3,3,3,3,4,4,4,5,5};           // ceil(R/16) (x-tiles = z-chunks)
// wave-tiles ordered level 15 -> 0 (longest first); count[l] = 2*czy*cx*cx
__constant__ int c_base[17]  = {0,1000,1900,2412,2892,3308,3524,3722,3902,4064,4128,4184,4240,4288,4328,4368,4376};

// weight fragments: [level][kz(3)][pair(5)][lane(64)][8 bf16] = 240 KB
__device__ __align__(16) unsigned short g_bfrag[NLVL*3*5*64*8];
// 16B zero source: halo lanes load from here unconditionally (L1-resident)
__device__ __align__(16) float g_zero[4] = {0.f, 0.f, 0.f, 0.f};

// ---------------------------------------------------------------------------
// Pack weights into MFMA A-operand fragments (weights-as-A, data-as-B).
// A[m=co][k]: m=lane&15, k=(lane>>4)*8+j; k -> tip=k>>4, ci=k&15;
// in-plane tap t2 = 2*pair + tip (t2==9 padded with zero weight).
// ---------------------------------------------------------------------------
__global__ void prep_bfrag(const float* __restrict__ wgt) {
    int tid = blockIdx.x * 256 + threadIdx.x;
    if (tid >= NLVL*3*5*64) return;
    int lane = tid & 63;
    int p    = (tid >> 6) % 5;
    int d    = (tid / (5*64)) % 3;
    int l    = tid / (3*5*64);
    int quad = lane >> 4, co = lane & 15;
    unsigned short v[8];
#pragma unroll
    for (int j = 0; j < 8; ++j) {
        int k   = quad*8 + j;
        int tip = k >> 4;
        int ci  = k & 15;
        int t2  = 2*p + tip;
        float f = (t2 < 9) ? wgt[((l*27 + d*9 + t2)*16 + ci)*16 + co] : 0.f;
        v[j] = __builtin_bit_cast(unsigned short, (__bf16)f);
    }
    u32x4 pk;
    pk[0] = (u32)v[0] | ((u32)v[1] << 16);
    pk[1] = (u32)v[2] | ((u32)v[3] << 16);
    pk[2] = (u32)v[4] | ((u32)v[5] << 16);
    pk[3] = (u32)v[6] | ((u32)v[7] << 16);
    *(u32x4*)&g_bfrag[(size_t)tid*8] = pk;
}

// ---------------------------------------------------------------------------
// Barrier-free streaming-z conv (R3 structure). Each WAVE owns a 16x * 4y
// tile streaming a 16-deep z-chunk. Staging loads are UNCONDITIONAL full-def
// vector loads from precomputed per-lane pointers (halo lanes -> g_zero,
// inc 0); z-edge planes take a uniform no-load branch. This removes the
// exec-masked partial-def load pattern suspected of serializing the 7 loads
// into sequential round-trips. Output stores are nontemporal.
// ---------------------------------------------------------------------------
__global__ __launch_bounds__(256, 2)
void conv_kernel(const float* __restrict__ in,
                 const float* __restrict__ bias,
                 float* __restrict__ out) {
    // per-wave 8KB region: two bf16 planes [yp 0..5][xp 0..17][ci 0..15] at +0/+4096
    __shared__ __align__(16) char slab[4*8192];

    const int t    = threadIdx.x;
    const int lane = t & 63;
    const int wv   = t >> 6;

    // bijective XCD-aware swizzle (m204 variant, NBLOCK % 8 != 0)
    int bswz;
    {
        const int q = NBLOCK / 8, r = NBLOCK % 8;
        int xcd = blockIdx.x % 8, i = blockIdx.x / 8;
        bswz = (xcd < r ? xcd * (q + 1) : r * (q + 1) + (xcd - r) * q) + i;
    }

    const int tid4 = bswz*4 + wv;
    int idx = 0;
#pragma unroll
    for (int i = 1; i < 16; ++i) if (tid4 >= c_base[i]) idx = i;
    const int l = 15 - idx;
    const int R = c_R[l], off = c_off[l], czy = c_czy[l], cx = c_cx[l];

    int local = tid4 - c_base[idx];
    int per_b = czy*cx*cx;
    int bb = local / per_b;         int r1 = local - bb*per_b;
    int zt = r1 / (czy*cx);         int r2 = r1 - zt*(czy*cx);
    int yt = r2 / cx;               int xt = r2 - yt*cx;
    const int z0 = zt*16;
    const int z1 = (z0 + 16 < R) ? z0 + 16 : R;
    const int y0 = yt*4, x0 = xt*16;
    const int steps = z1 - z0 + 2;

    const int quad = lane >> 4;
    const int m    = lane & 15;
    const int qh   = quad >> 1;

    // ---- weight fragments resident (15 x 16B per lane) ----
    bf16x8 bfr[15];
#pragma unroll
    for (int d = 0; d < 3; ++d)
#pragma unroll
        for (int p = 0; p < 5; ++p)
            bfr[d*5+p] = *(const bf16x8*)&g_bfrag[(size_t)(((l*3 + d)*5 + p)*64 + lane)*8];

    // ---- A-frag LDS base pointers (5 pairs; +PAR*4096 +r*576 folded as imm) ----
    const char* sbase = (const char*)slab + wv*8192;
    const char* arA[5];
    {
        const int T0[5] = {0, 64, 608, 1152, 1216};
        const int T1[5] = {32, 576, 640, 1184, 1216};
        const int ab = m*32 + (quad & 1)*16;
#pragma unroll
        for (int p = 0; p < 5; ++p) arA[p] = sbase + ab + (qh ? T1[p] : T0[p]);
    }
    char* wbase = (char*)slab + wv*8192 + lane*8;

    // ---- staging: plane = 432 f32x4 chunks; slot s covers chunk lane+s*64 ----
    // Per-lane precomputed pointers: in-range lanes walk the input z-planes
    // (inc = plane bytes); halo/OOB lanes sit on g_zero forever (inc = 0).
    const int  zsE = R*R*16;            // f32 elements per z-plane
    const u32  zsB = (u32)zsE*4;        // bytes per z-plane
    const long gstartE = ((long)bb*NTOT + off)*16;

    const char* ptr[7]; u32 inc[7];
#pragma unroll
    for (int s = 0; s < 7; ++s) {
        int c = lane + s*64;
        int yp = c/72; int rem = c - yp*72; int xp = rem>>2; int ci4 = (rem&3)<<2;
        int y = y0 + yp - 1, x = x0 + xp - 1;
        bool ok = (c < 432) && ((unsigned)y < (unsigned)R) && ((unsigned)x < (unsigned)R);
        long e = gstartE + (long)(z0-1)*zsE + ((long)y*R + x)*16 + ci4;
        ptr[s] = ok ? (const char*)(in + e) : (const char*)g_zero;
        inc[s] = ok ? zsB : 0u;
    }

    const f32x4 z4 = {0,0,0,0};
    f32x4 LA[7], LB[7];

    // ---- prologue: plane z0-1 -> LA -> buf0; plane z0 -> LB (held in regs) ----
    {
        if (z0 > 0) {
#pragma unroll
            for (int s = 0; s < 7; ++s) LA[s] = *(const f32x4*)ptr[s];
        } else {
#pragma unroll
            for (int s = 0; s < 7; ++s) LA[s] = z4;
        }
#pragma unroll
        for (int s = 0; s < 7; ++s) ptr[s] += inc[s];
#pragma unroll
        for (int s = 0; s < 7; ++s) LB[s] = *(const f32x4*)ptr[s];
#pragma unroll
        for (int s = 0; s < 7; ++s) ptr[s] += inc[s];
#pragma unroll
        for (int s = 0; s < 7; ++s) {
            bf16x4 h = {(__bf16)LA[s][0],(__bf16)LA[s][1],(__bf16)LA[s][2],(__bf16)LA[s][3]};
            *(bf16x4*)(wbase + s*512) = h;
        }
    }

    const bool xok = (x0 + m) < R;
    bool ywr[4];
#pragma unroll
    for (int r = 0; r < 4; ++r) ywr[r] = (y0 + r) < R;
    const f32x4 bv4 = *(const f32x4*)(bias + (l << 4) + (quad << 2));

    float* so[4];
#pragma unroll
    for (int r = 0; r < 4; ++r)
        so[r] = out + gstartE + (((long)z0*R + (y0 + r))*(long)R + (x0 + m))*16 + (quad << 2);

    f32x4 acc0[4], acc1[4], acc2[4];
#pragma unroll
    for (int r = 0; r < 4; ++r) { acc0[r] = z4; acc1[r] = z4; acc2[r] = z4; }

    int zl = z0 + 1;   // plane loaded by the next body

    // Body II: loads plane zl into LN; computes plane z0-1+II from buf(PAR);
    // cvt-writes LO (plane z0+II) into buf(PAR^1); AZ completes out plane II-2.
#define BODY(II, PAR, LN, LO, AX, AY, AZ, ENST)                                         \
    {                                                                                   \
        const bool zr = (zl <= z1) && (zl < R);                                         \
        if (zr) {                                                                       \
            _Pragma("unroll")                                                           \
            for (int s = 0; s < 7; ++s) LN[s] = *(const f32x4*)ptr[s];                  \
            _Pragma("unroll")                                                           \
            for (int s = 0; s < 7; ++s) ptr[s] += inc[s];                               \
        } else {                                                                       \
            _Pragma("unroll")                                                           \
            for (int s = 0; s < 7; ++s) LN[s] = z4;                                     \
        }                                                                               \
        ++zl;                                                                           \
        _Pragma("unroll")                                                               \
        for (int p = 0; p < 5; ++p) {                                                   \
            _Pragma("unroll")                                                           \
            for (int r = 0; r < 4; ++r) {                                               \
                bf16x8 af = *(const bf16x8*)(arA[p] + (PAR)*4096 + r*576);              \
                AX[r] = __builtin_amdgcn_mfma_f32_16x16x32_bf16(bfr[p],    af, AX[r], 0,0,0); \
                AY[r] = __builtin_amdgcn_mfma_f32_16x16x32_bf16(bfr[5+p],  af, AY[r], 0,0,0); \
                AZ[r] = __builtin_amdgcn_mfma_f32_16x16x32_bf16(bfr[10+p], af, AZ[r], 0,0,0); \
            }                                                                           \
        }                                                                               \
        _Pragma("unroll")                                                               \
        for (int s = 0; s < 7; ++s) {                                                   \
            bf16x4 h = {(__bf16)LO[s][0],(__bf16)LO[s][1],(__bf16)LO[s][2],(__bf16)LO[s][3]}; \
            *(bf16x4*)(wbase + ((PAR)^1)*4096 + s*512) = h;                             \
        }                                                                               \
        if ((ENST) && (II) < steps) {                                                   \
            _Pragma("unroll")                                                           \
            for (int r = 0; r < 4; ++r) {                                               \
                if (ywr[r] && xok) {                                                    \
                    f32x4 o_ = AZ[r] + bv4;                                             \
                    __builtin_nontemporal_store(o_, (f32x4*)so[r]);                     \
                }                                                                       \
                so[r] += zsE;                                                           \
            }                                                                           \
        }                                                                               \
        _Pragma("unroll")                                                               \
        for (int r = 0; r < 4; ++r) AZ[r] = z4;                                         \
    }

    BODY(0, 0, LA, LB, acc0, acc2, acc1, 0)
    BODY(1, 1, LB, LA, acc1, acc0, acc2, 0)
    BODY(2, 0, LA, LB, acc2, acc1, acc0, 1)
    BODY(3, 1, LB, LA, acc0, acc2, acc1, 1)
    BODY(4, 0, LA, LB, acc1, acc0, acc2, 1)
    BODY(5, 1, LB, LA, acc2, acc1, acc0, 1)
#pragma unroll 1
    for (int i = 6; i < steps; i += 6) {
        BODY(i+0, 0, LA, LB, acc0, acc2, acc1, 1)
        BODY(i+1, 1, LB, LA, acc1, acc0, acc2, 1)
        BODY(i+2, 0, LA, LB, acc2, acc1, acc0, 1)
        BODY(i+3, 1, LB, LA, acc0, acc2, acc1, 1)
        BODY(i+4, 0, LA, LB, acc1, acc0, acc2, 1)
        BODY(i+5, 1, LB, LA, acc2, acc1, acc0, 1)
    }
#undef BODY
}

extern "C" void kernel_launch(void* const* d_in, const int* in_sizes, int n_in,
                              void* d_out, int out_size, void* d_ws, size_t ws_size,
                              hipStream_t stream) {
    const float* inp = (const float*)d_in[0];
    const float* wgt = (const float*)d_in[1];
    const float* bia = (const float*)d_in[2];
    float* out = (float*)d_out;
    prep_bfrag<<<dim3((NLVL*3*5*64 + 255)/256), dim3(256), 0, stream>>>(wgt);
    conv_kernel<<<dim3(NBLOCK), dim3(256), 0, stream>>>(inp, bia, out);
}